// Round 4
// baseline (226.100 us; speedup 1.0000x reference)
//
#include <hip/hip_runtime.h>
#include <hip/hip_fp16.h>

#define N_PTS 100000
#define MU_F  100.0f

typedef unsigned int uint;
typedef _Float16 h2 __attribute__((ext_vector_type(2)));

// ---------------------------------------------------------------------------
// K1 fused prep: blocks [0,256) encode | [256,1819) transpose | [1819,1883) hist
// ---------------------------------------------------------------------------
#define ENC_BLKS 256
#define TR_BLKS  1563            // ceil(100000/64)
#define HIST_BLKS 64

__global__ __launch_bounds__(256) void k_prep(const float* __restrict__ x,
                                              const float* __restrict__ encW,
                                              const float* __restrict__ encB,
                                              const float* __restrict__ dec,
                                              const int* __restrict__ labels,
                                              float* __restrict__ enc,
                                              __half* __restrict__ decT,
                                              int* __restrict__ ghist) {
    int b = blockIdx.x;
    if (b < ENC_BLKS) {
        // ----- encode: enc[row] = x . encW[row,:] + encB[row]
        int row = b & 31;
        int chunk = b >> 5;              // 0..7
        const int CH = N_PTS / 8;        // 12500
        int base = chunk * CH;
        const float4* W4 = reinterpret_cast<const float4*>(encW + (size_t)row * N_PTS + base);
        const float4* x4 = reinterpret_cast<const float4*>(x + base);
        const int nv = CH / 4;           // 3125
        float acc = 0.f;
        for (int idx = threadIdx.x; idx < nv; idx += 256) {
            float4 w = W4[idx];
            float4 xv = x4[idx];
            acc += w.x * xv.x + w.y * xv.y + w.z * xv.z + w.w * xv.w;
        }
        #pragma unroll
        for (int off = 32; off > 0; off >>= 1) acc += __shfl_down(acc, off);
        __shared__ float sred[4];
        int wid = threadIdx.x >> 6;
        if ((threadIdx.x & 63) == 0) sred[wid] = acc;
        __syncthreads();
        if (threadIdx.x == 0) {
            float s = sred[0] + sred[1] + sred[2] + sred[3];
            if (chunk == 0) s += encB[row];
            atomicAdd(enc + row, s);
        }
    } else if (b < ENC_BLKS + TR_BLKS) {
        // ----- transpose dec [32,N] f32 -> decT [N,32] fp16
        __shared__ float tile[32][65];
        int j0 = (b - ENC_BLKS) * 64;
        int col = threadIdx.x & 63;
        int r0 = threadIdx.x >> 6;       // 0..3
        #pragma unroll
        for (int it = 0; it < 8; ++it) {
            int row = it * 4 + r0;
            int j = j0 + col;
            float v = (j < N_PTS) ? dec[(size_t)row * N_PTS + j] : 0.f;
            tile[row][col] = v;
        }
        __syncthreads();
        #pragma unroll
        for (int it = 0; it < 4; ++it) {
            int idx = it * 256 + threadIdx.x;
            int j = idx >> 4;            // 0..63
            int p = idx & 15;            // i-pair
            int jj = j0 + j;
            if (jj < N_PTS) {
                __half2 h = __halves2half2(__float2half(tile[2 * p][j]),
                                           __float2half(tile[2 * p + 1][j]));
                *reinterpret_cast<__half2*>(decT + (size_t)jj * 32 + 2 * p) = h;
            }
        }
    } else {
        // ----- label histogram (16 bins)
        __shared__ int lh[16];
        if (threadIdx.x < 16) lh[threadIdx.x] = 0;
        __syncthreads();
        int hb = b - (ENC_BLKS + TR_BLKS);
        for (int j = hb * 256 + threadIdx.x; j < N_PTS; j += HIST_BLKS * 256)
            atomicAdd(&lh[labels[j]], 1);
        __syncthreads();
        if (threadIdx.x < 16) atomicAdd(&ghist[threadIdx.x], lh[threadIdx.x]);
    }
}

// ---------------------------------------------------------------------------
// K2: counting-sort scatter (bases computed locally from ghist)
// ---------------------------------------------------------------------------
__global__ __launch_bounds__(256) void k_scatter(const int* __restrict__ labels,
                                                 const int* __restrict__ ghist,
                                                 int* __restrict__ gcursor,
                                                 int* __restrict__ perm) {
    __shared__ int lh[16], lbase[16], lcur[16], gb[16];
    const int CHUNK = 784;               // 128 * 784 >= 100000
    int start = blockIdx.x * CHUNK;
    int end = min(start + CHUNK, N_PTS);
    if (threadIdx.x < 16) { lh[threadIdx.x] = 0; lcur[threadIdx.x] = 0; }
    if (threadIdx.x == 0) {
        int run = 0;
        for (int c = 0; c < 16; ++c) { gb[c] = run; run += ghist[c]; }
    }
    __syncthreads();
    for (int j = start + threadIdx.x; j < end; j += 256)
        atomicAdd(&lh[labels[j]], 1);
    __syncthreads();
    if (threadIdx.x < 16)
        lbase[threadIdx.x] = gb[threadIdx.x] + atomicAdd(&gcursor[threadIdx.x], lh[threadIdx.x]);
    __syncthreads();
    for (int j = start + threadIdx.x; j < end; j += 256) {
        int c = labels[j];
        int lpos = atomicAdd(&lcur[c], 1);
        perm[lbase[c] + lpos] = j;
    }
}

// ---------------------------------------------------------------------------
// helper: thread i<32 computes invL[i] = 1/(sigmoid(enc.bw_w[i*16+c])*MU/60)^2
// ---------------------------------------------------------------------------
__device__ inline void build_invC(const float* __restrict__ encL,
                                  const float* __restrict__ bw_w,
                                  const float* __restrict__ bw_b,
                                  float* __restrict__ invCL, int c) {
    if (threadIdx.x < 32) {
        int r = threadIdx.x * 16 + c;
        float z = bw_b[r];
        const float* wr = bw_w + r * 32;
        #pragma unroll
        for (int p = 0; p < 32; ++p) z = fmaf(encL[p], wr[p], z);
        float s = 1.f / (1.f + __expf(-z));
        float wmu = s * (MU_F / 60.0f);
        invCL[threadIdx.x] = 1.f / (wmu * wmu);
    }
}

// ---------------------------------------------------------------------------
// K3: S partials. block = (c, ih, ch): 16 x 2 x 16 = 512 blocks x 512 thr.
// acc[16] per thread over half the i range; per-block sums to S_part (or
// global atomics in fallback mode).
// ---------------------------------------------------------------------------
__global__ __launch_bounds__(512, 4) void k_S_sorted(const float* __restrict__ enc_g,
                                                     const float* __restrict__ bw_w,
                                                     const float* __restrict__ bw_b,
                                                     const float* __restrict__ nd,
                                                     const int* __restrict__ perm,
                                                     const int* __restrict__ ghist,
                                                     float* __restrict__ S,
                                                     float* __restrict__ S_part) {
    __shared__ float encL[32], invCL[32];
    __shared__ float Sloc[512];
    __shared__ int baseSh[17];
    int b = blockIdx.x;
    int c = b & 15;
    int ih = (b >> 4) & 1;
    int ch = b >> 5;                     // 0..15
    if (threadIdx.x < 32) encL[threadIdx.x] = enc_g[threadIdx.x];
    if (threadIdx.x < 512) Sloc[threadIdx.x] = 0.f;
    if (threadIdx.x == 0) {
        int run = 0;
        for (int cc = 0; cc < 16; ++cc) { baseSh[cc] = run; run += ghist[cc]; }
        baseSh[16] = run;
    }
    __syncthreads();
    build_invC(encL, bw_w, bw_b, invCL, c);
    __syncthreads();

    float invC[16];
    #pragma unroll
    for (int i = 0; i < 16; ++i) invC[i] = invCL[ih * 16 + i];

    int bs = baseSh[c];
    int cnt = baseSh[c + 1] - bs;
    int lane = threadIdx.x & 63;
    int kk = lane & 31;
    int jh = lane >> 5;
    int gw = ch * 8 + (threadIdx.x >> 6);   // wave within (c,ih): 0..127
    const int nw = 16 * 8;                  // 128
    int npairs = (cnt + 1) >> 1;

    float acc[16];
    #pragma unroll
    for (int i = 0; i < 16; ++i) acc[i] = 0.f;

    for (int pp = gw; pp < npairs; pp += nw) {
        bool valid = (2 * pp + jh) < cnt;
        int p = valid ? (bs + 2 * pp + jh) : bs;
        int j = __builtin_nontemporal_load(&perm[p]);
        float d = __builtin_nontemporal_load(&nd[(size_t)j * 32 + kk]);
        float d2 = valid ? d * d : 1e30f;
        #pragma unroll
        for (int i = 0; i < 16; ++i)
            acc[i] += fmaxf(fmaf(-d2, invC[i], 1.0f), 0.f);
    }
    // combine the two j-halves of the wave
    #pragma unroll
    for (int i = 0; i < 16; ++i) acc[i] += __shfl_xor(acc[i], 32);
    if (jh == 0) {
        #pragma unroll
        for (int i = 0; i < 16; ++i) atomicAdd(&Sloc[i * 32 + kk], acc[i]);
    }
    __syncthreads();
    if (S_part) {
        if (threadIdx.x < 512)
            S_part[(size_t)b * 512 + threadIdx.x] = Sloc[threadIdx.x];
    } else {
        if (threadIdx.x < 512) {
            float v = Sloc[threadIdx.x];
            if (v != 0.f)
                atomicAdd(&S[(ih * 16 + (threadIdx.x >> 5)) * 32 + (threadIdx.x & 31)], v);
        }
    }
}

// ---------------------------------------------------------------------------
// K4: reduce partials into S. grid 64 = 16 ch-groups x 4 t-segments.
// ---------------------------------------------------------------------------
__global__ __launch_bounds__(256) void k_S_reduce(const float* __restrict__ S_part,
                                                  float* __restrict__ S) {
    int g = blockIdx.x >> 2;                       // ch 0..15
    int t = (blockIdx.x & 3) * 256 + threadIdx.x;  // 0..1023
    int ih = t >> 9;
    int p = t & 511;
    float s = 0.f;
    #pragma unroll
    for (int c = 0; c < 16; ++c) {
        int b = c + (ih << 4) + (g << 5);
        s += S_part[(size_t)b * 512 + p];
    }
    atomicAdd(&S[t], s);
}

// ---------------------------------------------------------------------------
// K5 (main): i-half split steered by blockIdx%8 (pseudo-XCD) so each XCD's
// gather working set is one 3.2MB half of decT (fits 4MiB L2). Streaming
// inputs use nontemporal loads. out accumulated via atomicAdd (zeroed).
// ---------------------------------------------------------------------------
__global__ __launch_bounds__(256, 8) void k_main(const float* __restrict__ enc_g,
                                                 const float* __restrict__ bw_w,
                                                 const float* __restrict__ bw_b,
                                                 const float* __restrict__ S_g,
                                                 const float* __restrict__ nd,
                                                 const int* __restrict__ nid,
                                                 const int* __restrict__ perm,
                                                 const int* __restrict__ ghist,
                                                 const __half* __restrict__ decT,
                                                 float* __restrict__ out) {
    __shared__ float encL[32], invCL[32];
    __shared__ int baseSh[17];
    int b = blockIdx.x;
    int lo3 = b & 7;
    int half = lo3 >> 2;                 // XCDs 0-3 -> half0, 4-7 -> half1
    int r = (b >> 3) * 4 + (lo3 & 3);    // 0..1023
    int c = r & 15;
    int ch = r >> 4;                     // 0..63
    if (threadIdx.x < 32) encL[threadIdx.x] = enc_g[threadIdx.x];
    if (threadIdx.x == 0) {
        int run = 0;
        for (int cc = 0; cc < 16; ++cc) { baseSh[cc] = run; run += ghist[cc]; }
        baseSh[16] = run;
    }
    __syncthreads();
    build_invC(encL, bw_w, bw_b, invCL, c);
    __syncthreads();

    int lane = threadIdx.x & 63;
    int kk = lane & 31;
    int jh = lane >> 5;

    float invC[16];
    h2 Eh[8];
    #pragma unroll
    for (int p = 0; p < 8; ++p) {
        int g0 = half * 16 + 2 * p;
        invC[2 * p]     = invCL[g0];
        invC[2 * p + 1] = invCL[g0 + 1];
        float E0 = encL[g0]     / S_g[g0 * 32 + kk]       * 16384.f;
        float E1 = encL[g0 + 1] / S_g[(g0 + 1) * 32 + kk] * 16384.f;
        Eh[p] = __builtin_bit_cast(h2, __builtin_amdgcn_cvt_pkrtz(E0, E1));
    }

    int bs = baseSh[c];
    int cnt = baseSh[c + 1] - bs;
    int gw = ch * 4 + (threadIdx.x >> 6);   // 0..255 within (c,half)
    const int nw = 64 * 4;                  // 256
    int npairs = (cnt + 1) >> 1;
    const __half* decH = decT + half * 16;

    for (int pp = gw; pp < npairs; pp += nw) {
        bool valid = (2 * pp + jh) < cnt;
        int p = valid ? (bs + 2 * pp + jh) : bs;
        int j = __builtin_nontemporal_load(&perm[p]);
        float d = __builtin_nontemporal_load(&nd[(size_t)j * 32 + kk]);
        int id = __builtin_nontemporal_load(&nid[(size_t)j * 32 + kk]);
        float d2 = d * d;
        const uint4* rp = reinterpret_cast<const uint4*>(decH + (size_t)id * 32);
        uint4 q0 = rp[0], q1 = rp[1];
        uint dv[8] = {q0.x, q0.y, q0.z, q0.w, q1.x, q1.y, q1.z, q1.w};
        float acc = 0.f;
        #pragma unroll
        for (int p2 = 0; p2 < 8; ++p2) {
            h2 f2 = __builtin_bit_cast(h2, dv[p2]);
            float w0 = fmaxf(fmaf(-d2, invC[2 * p2], 1.f), 0.f);
            float w1 = fmaxf(fmaf(-d2, invC[2 * p2 + 1], 1.f), 0.f);
#if __has_builtin(__builtin_amdgcn_fdot2)
            h2 wh = __builtin_bit_cast(h2, __builtin_amdgcn_cvt_pkrtz(w0, w1));
            h2 we = wh * Eh[p2];
            acc = __builtin_amdgcn_fdot2(we, f2, acc, false);
#else
            float2 Ef = __half22float2(__builtin_bit_cast(__half2, Eh[p2]));
            acc = fmaf(w0 * Ef.x, (float)f2.x, acc);
            acc = fmaf(w1 * Ef.y, (float)f2.y, acc);
#endif
        }
        #pragma unroll
        for (int off = 16; off > 0; off >>= 1) acc += __shfl_xor(acc, off);
        if (kk == 0 && valid) atomicAdd(&out[j], acc * (1.f / 16384.f));
    }
}

// ---------------------------------------------------------------------------
extern "C" void kernel_launch(void* const* d_in, const int* in_sizes, int n_in,
                              void* d_out, int out_size, void* d_ws, size_t ws_size,
                              hipStream_t stream) {
    const float* x     = (const float*)d_in[0];
    const float* enc_w = (const float*)d_in[1];
    const float* enc_b = (const float*)d_in[2];
    const float* dec   = (const float*)d_in[3];
    const float* bw_w  = (const float*)d_in[4];
    const float* bw_b  = (const float*)d_in[5];
    const float* nd    = (const float*)d_in[6];
    const int*   nid   = (const int*)d_in[7];
    const int*   labels= (const int*)d_in[8];
    float* out = (float*)d_out;

    // ws layout:
    //   [0,128)            enc (32 f)
    //   [128,4224)         S (1024 f)
    //   [4224,4288)        ghist (16 i)
    //   [4288,4352)        gcursor (16 i)
    //   [8192,408192)      perm (100000 i)
    //   [409600,6809600)   decT (N*32 fp16, 6.4 MB)
    //   [6815744,7864320)  S_part (512*512 f, 1 MB) -- if ws_size permits
    char* ws = (char*)d_ws;
    float* enc    = (float*)(ws + 0);
    float* S      = (float*)(ws + 128);
    int* ghist    = (int*)(ws + 4224);
    int* gcursor  = (int*)(ws + 4288);
    int* perm     = (int*)(ws + 8192);
    __half* decT  = (__half*)(ws + 409600);
    bool use_part = ws_size >= 7864320ull;
    float* S_part = use_part ? (float*)(ws + 6815744) : nullptr;

    (void)hipMemsetAsync(d_ws, 0, 4608, stream);    // enc, S, ghist, gcursor
    (void)hipMemsetAsync(d_out, 0, (size_t)N_PTS * 4, stream);
    k_prep<<<dim3(ENC_BLKS + TR_BLKS + HIST_BLKS), dim3(256), 0, stream>>>(
        x, enc_w, enc_b, dec, labels, enc, decT, ghist);
    k_scatter<<<dim3(128), dim3(256), 0, stream>>>(labels, ghist, gcursor, perm);
    k_S_sorted<<<dim3(512), dim3(512), 0, stream>>>(enc, bw_w, bw_b, nd, perm,
                                                    ghist, S, S_part);
    if (use_part)
        k_S_reduce<<<dim3(64), dim3(256), 0, stream>>>(S_part, S);
    k_main<<<dim3(2048), dim3(256), 0, stream>>>(enc, bw_w, bw_b, S, nd, nid,
                                                 perm, ghist, decT, out);
}

// Round 5
// 183.177 us; speedup vs baseline: 1.2343x; 1.2343x over previous
//
#include <hip/hip_runtime.h>
#include <hip/hip_fp16.h>

#define N_PTS 100000
#define MU_F  100.0f

typedef unsigned int uint;
typedef _Float16 h2 __attribute__((ext_vector_type(2)));

#define E_SCALE 16384.0f
#define E_SCALE_INV (1.0f / 16384.0f)

// ---------------------------------------------------------------------------
// K1 fused prep: blocks [0,256) encode | [256,1819) transpose | [1819,1883) hist
// ---------------------------------------------------------------------------
#define ENC_BLKS 256
#define TR_BLKS  1563            // ceil(100000/64)
#define HIST_BLKS 64

__global__ __launch_bounds__(256) void k_prep(const float* __restrict__ x,
                                              const float* __restrict__ encW,
                                              const float* __restrict__ encB,
                                              const float* __restrict__ dec,
                                              const int* __restrict__ labels,
                                              float* __restrict__ enc,
                                              __half* __restrict__ decT,
                                              int* __restrict__ ghist) {
    int b = blockIdx.x;
    if (b < ENC_BLKS) {
        // ----- encode: enc[row] = x . encW[row,:] + encB[row]
        int row = b & 31;
        int chunk = b >> 5;              // 0..7
        const int CH = N_PTS / 8;        // 12500
        int base = chunk * CH;
        const float4* W4 = reinterpret_cast<const float4*>(encW + (size_t)row * N_PTS + base);
        const float4* x4 = reinterpret_cast<const float4*>(x + base);
        const int nv = CH / 4;           // 3125
        float acc = 0.f;
        for (int idx = threadIdx.x; idx < nv; idx += 256) {
            float4 w = W4[idx];
            float4 xv = x4[idx];
            acc += w.x * xv.x + w.y * xv.y + w.z * xv.z + w.w * xv.w;
        }
        #pragma unroll
        for (int off = 32; off > 0; off >>= 1) acc += __shfl_down(acc, off);
        __shared__ float sred[4];
        int wid = threadIdx.x >> 6;
        if ((threadIdx.x & 63) == 0) sred[wid] = acc;
        __syncthreads();
        if (threadIdx.x == 0) {
            float s = sred[0] + sred[1] + sred[2] + sred[3];
            if (chunk == 0) s += encB[row];
            atomicAdd(enc + row, s);
        }
    } else if (b < ENC_BLKS + TR_BLKS) {
        // ----- transpose dec [32,N] f32 -> decT [N,32] fp16
        __shared__ float tile[32][65];
        int j0 = (b - ENC_BLKS) * 64;
        int col = threadIdx.x & 63;
        int r0 = threadIdx.x >> 6;       // 0..3
        #pragma unroll
        for (int it = 0; it < 8; ++it) {
            int row = it * 4 + r0;
            int j = j0 + col;
            float v = (j < N_PTS) ? dec[(size_t)row * N_PTS + j] : 0.f;
            tile[row][col] = v;
        }
        __syncthreads();
        #pragma unroll
        for (int it = 0; it < 4; ++it) {
            int idx = it * 256 + threadIdx.x;
            int j = idx >> 4;            // 0..63
            int p = idx & 15;            // i-pair
            int jj = j0 + j;
            if (jj < N_PTS) {
                __half2 h = __halves2half2(__float2half(tile[2 * p][j]),
                                           __float2half(tile[2 * p + 1][j]));
                *reinterpret_cast<__half2*>(decT + (size_t)jj * 32 + 2 * p) = h;
            }
        }
    } else {
        // ----- label histogram (16 bins)
        __shared__ int lh[16];
        if (threadIdx.x < 16) lh[threadIdx.x] = 0;
        __syncthreads();
        int hb = b - (ENC_BLKS + TR_BLKS);
        for (int j = hb * 256 + threadIdx.x; j < N_PTS; j += HIST_BLKS * 256)
            atomicAdd(&lh[labels[j]], 1);
        __syncthreads();
        if (threadIdx.x < 16) atomicAdd(&ghist[threadIdx.x], lh[threadIdx.x]);
    }
}

// ---------------------------------------------------------------------------
// K2: counting-sort scatter (bases computed locally from ghist)
// ---------------------------------------------------------------------------
__global__ __launch_bounds__(256) void k_scatter(const int* __restrict__ labels,
                                                 const int* __restrict__ ghist,
                                                 int* __restrict__ gcursor,
                                                 int* __restrict__ perm) {
    __shared__ int lh[16], lbase[16], lcur[16], gb[16];
    const int CHUNK = 784;               // 128 * 784 >= 100000
    int start = blockIdx.x * CHUNK;
    int end = min(start + CHUNK, N_PTS);
    if (threadIdx.x < 16) { lh[threadIdx.x] = 0; lcur[threadIdx.x] = 0; }
    if (threadIdx.x == 0) {
        int run = 0;
        for (int c = 0; c < 16; ++c) { gb[c] = run; run += ghist[c]; }
    }
    __syncthreads();
    for (int j = start + threadIdx.x; j < end; j += 256)
        atomicAdd(&lh[labels[j]], 1);
    __syncthreads();
    if (threadIdx.x < 16)
        lbase[threadIdx.x] = gb[threadIdx.x] + atomicAdd(&gcursor[threadIdx.x], lh[threadIdx.x]);
    __syncthreads();
    for (int j = start + threadIdx.x; j < end; j += 256) {
        int c = labels[j];
        int lpos = atomicAdd(&lcur[c], 1);
        perm[lbase[c] + lpos] = j;
    }
}

// ---------------------------------------------------------------------------
// helper: thread i<32 computes invL[i] = 1/(sigmoid(enc.bw_w[i*16+c])*MU/60)^2
// ---------------------------------------------------------------------------
__device__ inline void build_invC(const float* __restrict__ encL,
                                  const float* __restrict__ bw_w,
                                  const float* __restrict__ bw_b,
                                  float* __restrict__ invCL, int c) {
    if (threadIdx.x < 32) {
        int r = threadIdx.x * 16 + c;
        float z = bw_b[r];
        const float* wr = bw_w + r * 32;
        #pragma unroll
        for (int p = 0; p < 32; ++p) z = fmaf(encL[p], wr[p], z);
        float s = 1.f / (1.f + __expf(-z));
        float wmu = s * (MU_F / 60.0f);
        invCL[threadIdx.x] = 1.f / (wmu * wmu);
    }
}

// ---------------------------------------------------------------------------
// K3: S partials. block = (c, ih, ch): 16 x 2 x 16 = 512 blocks x 512 thr.
// ---------------------------------------------------------------------------
__global__ __launch_bounds__(512, 4) void k_S_sorted(const float* __restrict__ enc_g,
                                                     const float* __restrict__ bw_w,
                                                     const float* __restrict__ bw_b,
                                                     const float* __restrict__ nd,
                                                     const int* __restrict__ perm,
                                                     const int* __restrict__ ghist,
                                                     float* __restrict__ S,
                                                     float* __restrict__ S_part) {
    __shared__ float encL[32], invCL[32];
    __shared__ float Sloc[512];
    __shared__ int baseSh[17];
    int b = blockIdx.x;
    int c = b & 15;
    int ih = (b >> 4) & 1;
    int ch = b >> 5;                     // 0..15
    if (threadIdx.x < 32) encL[threadIdx.x] = enc_g[threadIdx.x];
    if (threadIdx.x < 512) Sloc[threadIdx.x] = 0.f;
    if (threadIdx.x == 0) {
        int run = 0;
        for (int cc = 0; cc < 16; ++cc) { baseSh[cc] = run; run += ghist[cc]; }
        baseSh[16] = run;
    }
    __syncthreads();
    build_invC(encL, bw_w, bw_b, invCL, c);
    __syncthreads();

    float invC[16];
    #pragma unroll
    for (int i = 0; i < 16; ++i) invC[i] = invCL[ih * 16 + i];

    int bs = baseSh[c];
    int cnt = baseSh[c + 1] - bs;
    int lane = threadIdx.x & 63;
    int kk = lane & 31;
    int jh = lane >> 5;
    int gw = ch * 8 + (threadIdx.x >> 6);   // wave within (c,ih): 0..127
    const int nw = 16 * 8;                  // 128
    int npairs = (cnt + 1) >> 1;

    float acc[16];
    #pragma unroll
    for (int i = 0; i < 16; ++i) acc[i] = 0.f;

    for (int pp = gw; pp < npairs; pp += nw) {
        bool valid = (2 * pp + jh) < cnt;
        int p = valid ? (bs + 2 * pp + jh) : bs;
        int j = __builtin_nontemporal_load(&perm[p]);
        float d = __builtin_nontemporal_load(&nd[(size_t)j * 32 + kk]);
        float d2 = valid ? d * d : 1e30f;
        #pragma unroll
        for (int i = 0; i < 16; ++i)
            acc[i] += fmaxf(fmaf(-d2, invC[i], 1.0f), 0.f);
    }
    #pragma unroll
    for (int i = 0; i < 16; ++i) acc[i] += __shfl_xor(acc[i], 32);
    if (jh == 0) {
        #pragma unroll
        for (int i = 0; i < 16; ++i) atomicAdd(&Sloc[i * 32 + kk], acc[i]);
    }
    __syncthreads();
    if (S_part) {
        if (threadIdx.x < 512)
            S_part[(size_t)b * 512 + threadIdx.x] = Sloc[threadIdx.x];
    } else {
        if (threadIdx.x < 512) {
            float v = Sloc[threadIdx.x];
            if (v != 0.f)
                atomicAdd(&S[(ih * 16 + (threadIdx.x >> 5)) * 32 + (threadIdx.x & 31)], v);
        }
    }
}

// ---------------------------------------------------------------------------
// K4: reduce partials into S (S pre-zeroed by memset).
// ---------------------------------------------------------------------------
__global__ __launch_bounds__(256) void k_S_reduce(const float* __restrict__ S_part,
                                                  float* __restrict__ S) {
    int g = blockIdx.x >> 2;                       // ch 0..15
    int t = (blockIdx.x & 3) * 256 + threadIdx.x;  // 0..1023
    int ih = t >> 9;
    int p = t & 511;
    float s = 0.f;
    #pragma unroll
    for (int c = 0; c < 16; ++c) {
        int b = c + (ih << 4) + (g << 5);
        s += S_part[(size_t)b * 512 + p];
    }
    atomicAdd(&S[t], s);
}

// ---------------------------------------------------------------------------
// K5 (main): cooperative-gather layout.
// 4 consecutive lanes load one 64B decT row (16B/lane) -> 16 lines/instr
// instead of 64 -> 4x fewer TCP line-lookups. Row (jh,kk) ownership rotates
// over 4 sub-steps s; (id,d2) redistributed via __shfl from the scalar-load
// layout lane=(jh,kk). Each lane covers i-quarter q=lane&3 with per-lane
// register constants (E for kk=R and R+16 only). Full-wave reduce, plain store.
// ---------------------------------------------------------------------------
__global__ __launch_bounds__(256, 6) void k_main(const float* __restrict__ enc_g,
                                                 const float* __restrict__ bw_w,
                                                 const float* __restrict__ bw_b,
                                                 const float* __restrict__ S_g,
                                                 const float* __restrict__ nd,
                                                 const int* __restrict__ nid,
                                                 const int* __restrict__ perm,
                                                 const int* __restrict__ ghist,
                                                 const __half* __restrict__ decT,
                                                 float* __restrict__ out) {
    __shared__ float encL[32], invCL[32];
    __shared__ float ELf[1024];          // E[i][kk] * E_SCALE
    __shared__ int baseSh[17];
    int c = blockIdx.x & 15;
    int ch = blockIdx.x >> 4;            // 0..95
    if (threadIdx.x < 32) encL[threadIdx.x] = enc_g[threadIdx.x];
    if (threadIdx.x == 0) {
        int run = 0;
        for (int cc = 0; cc < 16; ++cc) { baseSh[cc] = run; run += ghist[cc]; }
        baseSh[16] = run;
    }
    __syncthreads();
    build_invC(encL, bw_w, bw_b, invCL, c);
    for (int t = threadIdx.x; t < 1024; t += 256)
        ELf[t] = encL[t >> 5] / S_g[t] * E_SCALE;
    __syncthreads();

    int lane = threadIdx.x & 63;
    int kk = lane & 31;                  // scalar-load layout
    int jh = lane >> 5;
    int R = lane >> 2;                   // row sub-index 0..15
    int q = lane & 3;                    // i-quarter

    // per-lane constants: inv for i in [q*8, q*8+8); E for kk=R and kk=R+16
    float invq[8];
    h2 EhA[4], EhB[4];
    #pragma unroll
    for (int t = 0; t < 8; ++t) invq[t] = invCL[q * 8 + t];
    #pragma unroll
    for (int t = 0; t < 4; ++t) {
        int i0 = q * 8 + 2 * t, i1 = i0 + 1;
        EhA[t] = __builtin_bit_cast(h2, __builtin_amdgcn_cvt_pkrtz(
                     ELf[i0 * 32 + R], ELf[i1 * 32 + R]));
        EhB[t] = __builtin_bit_cast(h2, __builtin_amdgcn_cvt_pkrtz(
                     ELf[i0 * 32 + R + 16], ELf[i1 * 32 + R + 16]));
    }

    int bs = baseSh[c];
    int cnt = baseSh[c + 1] - bs;
    int wv = ch * 4 + (threadIdx.x >> 6);   // wave within c: 0..383
    const int nw = 96 * 4;                  // 384
    int npairs = (cnt + 1) >> 1;
    const uint4* decQ = reinterpret_cast<const uint4*>(decT);

    int pp = wv;
    int jl = 0, idl = 0; float d2l = 1e30f; bool validl = false;
    if (pp < npairs) {
        validl = (2 * pp + jh) < cnt;
        int p = validl ? (bs + 2 * pp + jh) : bs;
        jl = __builtin_nontemporal_load(&perm[p]);
        float d = __builtin_nontemporal_load(&nd[(size_t)jl * 32 + kk]);
        idl = __builtin_nontemporal_load(&nid[(size_t)jl * 32 + kk]);
        d2l = validl ? d * d : 1e30f;
    }

    while (pp < npairs) {
        int pn = pp + nw;
        // redistribute (id, d2) for the 4 sub-steps; rows r = s*16 + R
        int   id0 = __shfl(idl, 0 * 16 + R);
        int   id1 = __shfl(idl, 1 * 16 + R);
        int   id2 = __shfl(idl, 2 * 16 + R);
        int   id3 = __shfl(idl, 3 * 16 + R);
        float d20 = __shfl(d2l, 0 * 16 + R);
        float d21 = __shfl(d2l, 1 * 16 + R);
        float d22 = __shfl(d2l, 2 * 16 + R);
        float d23 = __shfl(d2l, 3 * 16 + R);
        // cooperative row gathers: 4 lanes per 64B row, 16B each
        uint4 r0 = decQ[(size_t)id0 * 4 + q];
        uint4 r1 = decQ[(size_t)id1 * 4 + q];
        uint4 r2 = decQ[(size_t)id2 * 4 + q];
        uint4 r3 = decQ[(size_t)id3 * 4 + q];
        // prefetch next iteration's scalars (independent of current compute)
        int jn = 0, idn = 0; float d2n = 1e30f; bool validn = false;
        if (pn < npairs) {
            validn = (2 * pn + jh) < cnt;
            int p = validn ? (bs + 2 * pn + jh) : bs;
            jn = __builtin_nontemporal_load(&perm[p]);
            float d = __builtin_nontemporal_load(&nd[(size_t)jn * 32 + kk]);
            idn = __builtin_nontemporal_load(&nid[(size_t)jn * 32 + kk]);
            d2n = validn ? d * d : 1e30f;
        }

        float a0 = 0.f, a1 = 0.f, a2 = 0.f, a3 = 0.f;
        #pragma unroll
        for (int t = 0; t < 4; ++t) {
            uint dw0 = (t == 0) ? r0.x : (t == 1) ? r0.y : (t == 2) ? r0.z : r0.w;
            uint dw1 = (t == 0) ? r1.x : (t == 1) ? r1.y : (t == 2) ? r1.z : r1.w;
            uint dw2 = (t == 0) ? r2.x : (t == 1) ? r2.y : (t == 2) ? r2.z : r2.w;
            uint dw3 = (t == 0) ? r3.x : (t == 1) ? r3.y : (t == 2) ? r3.z : r3.w;
            float i0v = invq[2 * t], i1v = invq[2 * t + 1];
            // s=0: j0, kk=R (EhA)
            {
                float w0 = fmaxf(fmaf(-d20, i0v, 1.f), 0.f);
                float w1 = fmaxf(fmaf(-d20, i1v, 1.f), 0.f);
                h2 wh = __builtin_bit_cast(h2, __builtin_amdgcn_cvt_pkrtz(w0, w1));
                a0 = __builtin_amdgcn_fdot2(wh * EhA[t], __builtin_bit_cast(h2, dw0), a0, false);
            }
            // s=1: j0, kk=R+16 (EhB)
            {
                float w0 = fmaxf(fmaf(-d21, i0v, 1.f), 0.f);
                float w1 = fmaxf(fmaf(-d21, i1v, 1.f), 0.f);
                h2 wh = __builtin_bit_cast(h2, __builtin_amdgcn_cvt_pkrtz(w0, w1));
                a1 = __builtin_amdgcn_fdot2(wh * EhB[t], __builtin_bit_cast(h2, dw1), a1, false);
            }
            // s=2: j1, kk=R (EhA)
            {
                float w0 = fmaxf(fmaf(-d22, i0v, 1.f), 0.f);
                float w1 = fmaxf(fmaf(-d22, i1v, 1.f), 0.f);
                h2 wh = __builtin_bit_cast(h2, __builtin_amdgcn_cvt_pkrtz(w0, w1));
                a2 = __builtin_amdgcn_fdot2(wh * EhA[t], __builtin_bit_cast(h2, dw2), a2, false);
            }
            // s=3: j1, kk=R+16 (EhB)
            {
                float w0 = fmaxf(fmaf(-d23, i0v, 1.f), 0.f);
                float w1 = fmaxf(fmaf(-d23, i1v, 1.f), 0.f);
                h2 wh = __builtin_bit_cast(h2, __builtin_amdgcn_cvt_pkrtz(w0, w1));
                a3 = __builtin_amdgcn_fdot2(wh * EhB[t], __builtin_bit_cast(h2, dw3), a3, false);
            }
        }
        float u = a0 + a1;               // j0 partial
        float v = a2 + a3;               // j1 partial
        #pragma unroll
        for (int off = 32; off > 0; off >>= 1) {
            u += __shfl_xor(u, off);
            v += __shfl_xor(v, off);
        }
        if (lane == 0) out[jl] = u * E_SCALE_INV;
        if (lane == 32 && validl) out[jl] = v * E_SCALE_INV;

        jl = jn; idl = idn; d2l = d2n; validl = validn;
        pp = pn;
    }
}

// ---------------------------------------------------------------------------
extern "C" void kernel_launch(void* const* d_in, const int* in_sizes, int n_in,
                              void* d_out, int out_size, void* d_ws, size_t ws_size,
                              hipStream_t stream) {
    const float* x     = (const float*)d_in[0];
    const float* enc_w = (const float*)d_in[1];
    const float* enc_b = (const float*)d_in[2];
    const float* dec   = (const float*)d_in[3];
    const float* bw_w  = (const float*)d_in[4];
    const float* bw_b  = (const float*)d_in[5];
    const float* nd    = (const float*)d_in[6];
    const int*   nid   = (const int*)d_in[7];
    const int*   labels= (const int*)d_in[8];
    float* out = (float*)d_out;

    // ws layout:
    //   [0,128)            enc (32 f)
    //   [128,4224)         S (1024 f)
    //   [4224,4288)        ghist (16 i)
    //   [4288,4352)        gcursor (16 i)
    //   [8192,408192)      perm (100000 i)
    //   [408576,6808576)   decT (N*32 fp16, 6.4 MB)
    //   [6811648,7860224)  S_part (512*512 f, 1 MB) -- if ws_size permits
    char* ws = (char*)d_ws;
    float* enc    = (float*)(ws + 0);
    float* S      = (float*)(ws + 128);
    int* ghist    = (int*)(ws + 4224);
    int* gcursor  = (int*)(ws + 4288);
    int* perm     = (int*)(ws + 8192);
    __half* decT  = (__half*)(ws + 408576);
    bool use_part = ws_size >= 7860224ull;
    float* S_part = use_part ? (float*)(ws + 6811648) : nullptr;

    (void)hipMemsetAsync(d_ws, 0, 4352, stream);    // enc, S, ghist, gcursor
    k_prep<<<dim3(ENC_BLKS + TR_BLKS + HIST_BLKS), dim3(256), 0, stream>>>(
        x, enc_w, enc_b, dec, labels, enc, decT, ghist);
    k_scatter<<<dim3(128), dim3(256), 0, stream>>>(labels, ghist, gcursor, perm);
    k_S_sorted<<<dim3(512), dim3(512), 0, stream>>>(enc, bw_w, bw_b, nd, perm,
                                                    ghist, S, S_part);
    if (use_part)
        k_S_reduce<<<dim3(64), dim3(256), 0, stream>>>(S_part, S);
    k_main<<<dim3(1536), dim3(256), 0, stream>>>(enc, bw_w, bw_b, S, nd, nid,
                                                 perm, ghist, decT, out);
}